// Round 2
// baseline (2665.513 us; speedup 1.0000x reference)
//
#include <hip/hip_runtime.h>
#include <math.h>

#define B 64
#define N 1024
#define D 256
#define H 256
#define G3 768            // 3*H
#define NUM_BAGS (B*N)
#define OUTW (D+H)
#define NB 12             // nodes batched per weight pass (LDS = 55.4 KB < 64 KB)
#define NBLK 256          // persistent blocks, one per CU

typedef _Float16 h2_t __attribute__((ext_vector_type(2)));
typedef unsigned int uint32;

__device__ __forceinline__ float sigmoidf_(float x) { return 1.0f / (1.0f + expf(-x)); }

__device__ __forceinline__ float dot2f(uint32 a, uint32 b, float c) {
#if __has_builtin(__builtin_amdgcn_fdot2)
    return __builtin_amdgcn_fdot2(__builtin_bit_cast(h2_t, a), __builtin_bit_cast(h2_t, b), c, false);
#else
    h2_t x = __builtin_bit_cast(h2_t, a), y = __builtin_bit_cast(h2_t, b);
    return c + (float)x[0] * (float)y[0] + (float)x[1] * (float)y[1];
#endif
}

// ---------------------------------------------------------------------------
// Kernel 1: w_ihT transpose, wpack f16 packing, zero hist/cnt/nlv
// ---------------------------------------------------------------------------
__global__ void k_prep(const float* __restrict__ w_ih, const float* __restrict__ w_hh,
                       float* __restrict__ w_ihT, uint32* __restrict__ wpack,
                       int* __restrict__ hist, int* __restrict__ cnt, int* __restrict__ nlv) {
    int idx = blockIdx.x * blockDim.x + threadIdx.x;
    if (idx < G3 * D) {
        int j = idx / D;
        int d = idx % D;
        w_ihT[d * G3 + j] = w_ih[idx];
    }
    if (idx < G3 * 128) {
        int j = idx / 128;
        int m = idx % 128;
        float w0 = w_hh[j * D + 2 * m];
        float w1 = w_hh[j * D + 2 * m + 1];
        h2_t v = { (_Float16)w0, (_Float16)w1 };
        wpack[m * G3 + j] = __builtin_bit_cast(uint32, v);
    }
    if (idx < 1024) { hist[idx] = 0; cnt[idx] = 0; }
    if (idx == 0) *nlv = 0;
}

// ---------------------------------------------------------------------------
// Kernel 1b: depth[b][i] = depth[parent]+1 (0 for roots / malformed parents).
// 64 blocks, thread 0 walks its batch's 1024 nodes in LDS (~15 us, all batches
// concurrent).
// ---------------------------------------------------------------------------
__global__ void k_depth(const int* __restrict__ lp_all, int* __restrict__ depth) {
    __shared__ int slp[N];
    __shared__ int sd[N];
    int b = blockIdx.x;
    for (int t = threadIdx.x; t < N; t += 256) slp[t] = lp_all[(size_t)b * N + t];
    __syncthreads();
    if (threadIdx.x == 0) {
        sd[0] = 0;
        for (int i = 1; i < N; ++i) {
            int p = slp[i];
            sd[i] = ((unsigned)p < (unsigned)i) ? sd[p] + 1 : 0;
        }
    }
    __syncthreads();
    for (int t = threadIdx.x; t < N; t += 256) depth[(size_t)b * N + t] = sd[t];
}

__global__ void k_hist(const int* __restrict__ depth, int* __restrict__ hist) {
    int g = blockIdx.x * 256 + threadIdx.x;
    atomicAdd(&hist[depth[g]], 1);
}

// 1 block x 1024: inclusive Hillis-Steele -> exclusive base, cursor copy, nlv
__global__ void k_scan(const int* __restrict__ hist, int* __restrict__ base,
                       int* __restrict__ cursor, int* __restrict__ nlv) {
    __shared__ int tmp[1024];
    int t = threadIdx.x;
    int v = hist[t];
    tmp[t] = v;
    __syncthreads();
    for (int off = 1; off < 1024; off <<= 1) {
        int y = (t >= off) ? tmp[t - off] : 0;
        __syncthreads();
        tmp[t] += y;
        __syncthreads();
    }
    int inc = tmp[t];
    base[t] = inc - v;
    cursor[t] = inc - v;
    if (t == 1023) base[1024] = inc;
    if (v > 0) atomicMax(nlv, t + 1);
}

__global__ void k_scatter(const int* __restrict__ depth, int* __restrict__ cursor,
                          int* __restrict__ order) {
    int g = blockIdx.x * 256 + threadIdx.x;
    int pos = atomicAdd(&cursor[depth[g]], 1);
    order[pos] = g;
}

// ---------------------------------------------------------------------------
// Kernel 2: TE2 = type_emb @ w_ihT (300x768), PE2 = pos_table @ w_ihT (1000x768)
// ---------------------------------------------------------------------------
__global__ void k_table_gemm(const float* __restrict__ type_emb, const float* __restrict__ pos_table,
                             const float* __restrict__ w_ihT,
                             float* __restrict__ TE2, float* __restrict__ PE2) {
    __shared__ float row[D];
    int r = blockIdx.x;
    const float* src;
    float* dst;
    if (r < 300) { src = type_emb + (size_t)r * D;          dst = TE2 + (size_t)r * G3; }
    else         { src = pos_table + (size_t)(r - 300) * D; dst = PE2 + (size_t)(r - 300) * G3; }
    int k = threadIdx.x;
    row[k] = src[k];
    __syncthreads();
    float a0 = 0.f, a1 = 0.f, a2 = 0.f;
#pragma unroll 8
    for (int d = 0; d < D; ++d) {
        float p = row[d];
        const float* w = w_ihT + d * G3;
        a0 += p * w[k];
        a1 += p * w[k + 256];
        a2 += p * w[k + 512];
    }
    dst[k] = a0; dst[k + 256] = a1; dst[k + 512] = a2;
}

// ---------------------------------------------------------------------------
// Kernel 3: output columns [0, D)
// ---------------------------------------------------------------------------
__global__ void k_embed_out(const int* __restrict__ node_types, const int* __restrict__ child_pos,
                            const int* __restrict__ node_vals, const int* __restrict__ offsets,
                            const float* __restrict__ type_emb, const float* __restrict__ pos_table,
                            const float* __restrict__ token_emb, float* __restrict__ out, int Ltot) {
    int tid = threadIdx.x;
    int bag = blockIdx.x * 4 + (tid >> 6);
    int q   = (tid & 63) * 4;
    int b = bag >> 10;
    int i = bag & 1023;
    int t = node_types[bag];
    int c = child_pos[bag];
    int start = offsets[bag];
    int end   = (bag + 1 < NUM_BAGS) ? offsets[bag + 1] : Ltot;

    float4 s = make_float4(0.f, 0.f, 0.f, 0.f);
    for (int l = start; l < end; ++l) {
        float4 v = *(const float4*)(token_emb + (size_t)node_vals[l] * D + q);
        s.x += v.x; s.y += v.y; s.z += v.z; s.w += v.w;
    }
    int cnt = end - start; if (cnt < 1) cnt = 1;
    float inv = 4.0f / (float)cnt;
    float4 a = *(const float4*)(type_emb + (size_t)t * D + q);
    float4 p = *(const float4*)(pos_table + (size_t)c * D + q);
    float4 r;
    r.x = 4.f * a.x + 0.25f * p.x + inv * s.x;
    r.y = 4.f * a.y + 0.25f * p.y + inv * s.y;
    r.z = 4.f * a.z + 0.25f * p.z + inv * s.z;
    r.w = 4.f * a.w + 0.25f * p.w + inv * s.w;
    *(float4*)(out + ((size_t)i * B + b) * OUTW + q) = r;
}

// ---------------------------------------------------------------------------
// Kernel 4: level-scheduled GRU. Nodes sorted by tree depth; within a level
// all nodes are independent and all parents are complete. 256 persistent
// blocks; each grabs groups of NB=12 nodes. Per group: one stream of wpack
// from L2 feeds 12 accumulators (12x amortization of weight traffic, the L2-BW
// bottleneck that capped the previous kernel). Parent h kept f32 in regs for
// the z*pv blend (precision-identical to prior passing kernels). ~25 grid
// barriers total via per-level agent-scope counters (all 256 blocks resident:
// 1 block/CU, 55 KB LDS, VGPR<=170 per __launch_bounds__(768,3)).
// ---------------------------------------------------------------------------
__global__ void __launch_bounds__(768, 3) k_gru_lvl(
        const int* __restrict__ node_types, const int* __restrict__ child_pos,
        const int* __restrict__ last_parent,
        const float* __restrict__ TE2, const float* __restrict__ PE2,
        const uint32* __restrict__ wpack,
        const float* __restrict__ b_ih, const float* __restrict__ b_hh,
        float* __restrict__ out,
        const int* __restrict__ order, const int* __restrict__ lvlbase,
        const int* __restrict__ nlvp, int* __restrict__ cnt) {
    __shared__ __align__(16) uint32 sp[NB][128];   // packed f16 parent h
    __shared__ float gbuf[NB][G3];                 // r,z: gi+gh ; n: gh
    __shared__ float gni[NB][H];                   // n: gi part
    __shared__ int   meta[NB][2];                  // g, parent

    const int j = threadIdx.x;
    const int bid = blockIdx.x;
    const float bi = b_ih[j], bh = b_hh[j];
    const int nlv = *nlvp;

    for (int L = 0; L < nlv; ++L) {
        const int s = lvlbase[L], e = lvlbase[L + 1];
        const int nG = (e - s + NB - 1) / NB;
        for (int q = bid; q < nG; q += NBLK) {
            const int k0 = s + q * NB;
            const int cn = min(NB, e - k0);
            if (j < cn) {
                int g = order[k0 + j];
                meta[j][0] = g;
                meta[j][1] = last_parent[g];
            }
            __syncthreads();

            const int lim = cn << 8;               // cn*256 (wave-aligned guard)
            // parent h rows -> f32 regs (pvr) + packed f16 pairs -> sp
            float pvr[4];
#pragma unroll
            for (int u = 0; u < 4; ++u) {
                const int qq = j + u * 768;
                float hv = 0.f;
                if (qq < lim) {
                    const int n = qq >> 8, jj = qq & 255;
                    const int g = meta[n][0];
                    const int i = g & (N - 1), b = g >> 10;
                    const int p = meta[n][1];
                    if (i > 0 && (unsigned)p < (unsigned)i)
                        hv = out[((size_t)p * B + b) * OUTW + D + jj];
                    float ho = __shfl_xor(hv, 1);
                    if (!(jj & 1)) {
                        h2_t v2 = { (_Float16)hv, (_Float16)ho };
                        sp[n][jj >> 1] = __builtin_bit_cast(uint32, v2);
                    }
                }
                pvr[u] = hv;
            }

            // gi = 4*te + 0.25*pe + bi per node (issued before the dot)
            float gi[NB];
#pragma unroll
            for (int n = 0; n < NB; ++n) {
                float te = 0.f, pe = 0.f;
                if (n < cn) {
                    const int g = meta[n][0];
                    te = TE2[(size_t)node_types[g] * G3 + j];
                    pe = PE2[(size_t)child_pos[g] * G3 + j];
                }
                gi[n] = 4.f * te + 0.25f * pe + bi;
            }

            float acc[NB];
#pragma unroll
            for (int n = 0; n < NB; ++n) acc[n] = 0.f;
            __syncthreads();                       // sp ready

            // ---- batched dot: one wpack stream feeds NB nodes ----
#pragma unroll 4
            for (int m = 0; m < 128; m += 4) {
                const uint32 w0 = wpack[(m + 0) * G3 + j];
                const uint32 w1 = wpack[(m + 1) * G3 + j];
                const uint32 w2 = wpack[(m + 2) * G3 + j];
                const uint32 w3 = wpack[(m + 3) * G3 + j];
#pragma unroll
                for (int n = 0; n < NB; ++n) {
                    const uint4 h4 = *(const uint4*)(&sp[n][m]);
                    acc[n] = dot2f(w0, h4.x, acc[n]);
                    acc[n] = dot2f(w1, h4.y, acc[n]);
                    acc[n] = dot2f(w2, h4.z, acc[n]);
                    acc[n] = dot2f(w3, h4.w, acc[n]);
                }
            }

#pragma unroll
            for (int n = 0; n < NB; ++n) {
                if (n < cn) {
                    const float gh = acc[n] + bh;
                    if (j < 512) gbuf[n][j] = gi[n] + gh;
                    else { gbuf[n][j] = gh; gni[n][j - 512] = gi[n]; }
                }
            }
            __syncthreads();                       // gbuf ready

            // ---- activations + h store ----
#pragma unroll
            for (int u = 0; u < 4; ++u) {
                const int qq = j + u * 768;
                if (qq < lim) {
                    const int n = qq >> 8, jj = qq & 255;
                    const float r  = sigmoidf_(gbuf[n][jj]);
                    const float z  = sigmoidf_(gbuf[n][H + jj]);
                    const float nn = tanhf(gni[n][jj] + r * gbuf[n][2 * H + jj]);
                    const float h  = (1.f - z) * nn + z * pvr[u];
                    const int g = meta[n][0];
                    const int i = g & (N - 1), b = g >> 10;
                    out[((size_t)i * B + b) * OUTW + D + jj] = h;
                }
            }
            __syncthreads();                       // protect meta/sp/gbuf reuse
        }
        // ---- level barrier (skip after last level) ----
        if (L + 1 < nlv) {
            if (j == 0) {
                __hip_atomic_fetch_add(&cnt[L], 1, __ATOMIC_RELEASE, __HIP_MEMORY_SCOPE_AGENT);
                while (__hip_atomic_load(&cnt[L], __ATOMIC_ACQUIRE, __HIP_MEMORY_SCOPE_AGENT) < NBLK)
                    __builtin_amdgcn_s_sleep(1);
            }
            __syncthreads();
        }
    }
}

// ---------------------------------------------------------------------------
extern "C" void kernel_launch(void* const* d_in, const int* in_sizes, int n_in,
                              void* d_out, int out_size, void* d_ws, size_t ws_size,
                              hipStream_t stream) {
    const int*   node_types  = (const int*)d_in[0];
    const int*   node_vals   = (const int*)d_in[1];
    const int*   offsets     = (const int*)d_in[2];
    const int*   last_parent = (const int*)d_in[3];
    const int*   child_pos   = (const int*)d_in[4];
    const float* type_emb    = (const float*)d_in[5];
    const float* pos_table   = (const float*)d_in[6];
    const float* token_emb   = (const float*)d_in[7];
    const float* w_ih        = (const float*)d_in[8];
    const float* w_hh        = (const float*)d_in[9];
    const float* b_ih        = (const float*)d_in[10];
    const float* b_hh        = (const float*)d_in[11];
    float* out = (float*)d_out;

    // Workspace: w_ihT | TE2 | PE2 | wpack | depth | order | hist | base |
    //            cursor | nlv | cnt   (~5.7 MB)
    float*  ws      = (float*)d_ws;
    float*  w_ihT   = ws;
    float*  TE2     = w_ihT + (size_t)G3 * D;
    float*  PE2     = TE2 + (size_t)300 * G3;
    uint32* wpack   = (uint32*)(PE2 + (size_t)1000 * G3);
    int*    depth   = (int*)(wpack + (size_t)G3 * 128);
    int*    order   = depth + NUM_BAGS;
    int*    hist    = order + NUM_BAGS;
    int*    lvlbase = hist + 1024;          // 1025 ints
    int*    cursor  = lvlbase + 1025;
    int*    nlv     = cursor + 1024;
    int*    cnt     = nlv + 1;
    int Ltot = in_sizes[1];

    hipLaunchKernelGGL(k_prep, dim3((G3 * D + 255) / 256), dim3(256), 0, stream,
                       w_ih, w_hh, w_ihT, wpack, hist, cnt, nlv);
    hipLaunchKernelGGL(k_depth, dim3(B), dim3(256), 0, stream, last_parent, depth);
    hipLaunchKernelGGL(k_hist, dim3(NUM_BAGS / 256), dim3(256), 0, stream, depth, hist);
    hipLaunchKernelGGL(k_scan, dim3(1), dim3(1024), 0, stream, hist, lvlbase, cursor, nlv);
    hipLaunchKernelGGL(k_scatter, dim3(NUM_BAGS / 256), dim3(256), 0, stream, depth, cursor, order);
    hipLaunchKernelGGL(k_table_gemm, dim3(1300), dim3(256), 0, stream,
                       type_emb, pos_table, w_ihT, TE2, PE2);
    hipLaunchKernelGGL(k_embed_out, dim3(NUM_BAGS / 4), dim3(256), 0, stream,
                       node_types, child_pos, node_vals, offsets,
                       type_emb, pos_table, token_emb, out, Ltot);
    hipLaunchKernelGGL(k_gru_lvl, dim3(NBLK), dim3(768), 0, stream,
                       node_types, child_pos, last_parent, TE2, PE2, wpack, b_ih, b_hh,
                       out, order, lvlbase, nlv, cnt);
}

// Round 4
// 1557.777 us; speedup vs baseline: 1.7111x; 1.7111x over previous
//
#include <hip/hip_runtime.h>
#include <hip/hip_cooperative_groups.h>
#include <math.h>

namespace cg = cooperative_groups;

#define B 64
#define N 1024
#define D 256
#define H 256
#define G3 768            // 3*H
#define NUM_BAGS (B*N)
#define OUTW (D+H)
#define NB 12             // nodes batched per weight pass (LDS = 55.4 KB)
#define NBLK 256          // persistent blocks, one per CU (cooperative)

typedef _Float16 h2_t __attribute__((ext_vector_type(2)));
typedef unsigned int uint32;

__device__ __forceinline__ float sigmoidf_(float x) { return 1.0f / (1.0f + expf(-x)); }

__device__ __forceinline__ float dot2f(uint32 a, uint32 b, float c) {
#if __has_builtin(__builtin_amdgcn_fdot2)
    return __builtin_amdgcn_fdot2(__builtin_bit_cast(h2_t, a), __builtin_bit_cast(h2_t, b), c, false);
#else
    h2_t x = __builtin_bit_cast(h2_t, a), y = __builtin_bit_cast(h2_t, b);
    return c + (float)x[0] * (float)y[0] + (float)x[1] * (float)y[1];
#endif
}

// ---------------------------------------------------------------------------
// Kernel 1: w_ihT transpose, wpack f16 packing, zero hist/nlv
// ---------------------------------------------------------------------------
__global__ void k_prep(const float* __restrict__ w_ih, const float* __restrict__ w_hh,
                       float* __restrict__ w_ihT, uint32* __restrict__ wpack,
                       int* __restrict__ hist, int* __restrict__ nlv) {
    int idx = blockIdx.x * blockDim.x + threadIdx.x;
    if (idx < G3 * D) {
        int j = idx / D;
        int d = idx % D;
        w_ihT[d * G3 + j] = w_ih[idx];
    }
    if (idx < G3 * 128) {
        int j = idx / 128;
        int m = idx % 128;
        float w0 = w_hh[j * D + 2 * m];
        float w1 = w_hh[j * D + 2 * m + 1];
        h2_t v = { (_Float16)w0, (_Float16)w1 };
        wpack[m * G3 + j] = __builtin_bit_cast(uint32, v);
    }
    if (idx < 1024) hist[idx] = 0;
    if (idx == 0) *nlv = 0;
}

// ---------------------------------------------------------------------------
// Kernel 1b: depth[b][i] = depth[parent]+1 (0 for roots / malformed parents)
// + per-tree LDS histogram merged with ~25 spread global RMWs per block.
// ---------------------------------------------------------------------------
__global__ void k_depth(const int* __restrict__ lp_all, int* __restrict__ depth,
                        int* __restrict__ hist) {
    __shared__ int slp[N];
    __shared__ int sd[N];
    __shared__ int lh[1024];
    int b = blockIdx.x;
    for (int t = threadIdx.x; t < N; t += 256) {
        slp[t] = lp_all[(size_t)b * N + t];
        lh[t] = 0;
    }
    __syncthreads();
    if (threadIdx.x == 0) {
        sd[0] = 0;
        for (int i = 1; i < N; ++i) {
            int p = slp[i];
            sd[i] = ((unsigned)p < (unsigned)i) ? sd[p] + 1 : 0;
        }
    }
    __syncthreads();
    for (int t = threadIdx.x; t < N; t += 256) {
        depth[(size_t)b * N + t] = sd[t];
        atomicAdd(&lh[sd[t]], 1);          // LDS atomic, cheap
    }
    __syncthreads();
    for (int t = threadIdx.x; t < 1024; t += 256)
        if (lh[t] > 0) atomicAdd(&hist[t], lh[t]);
}

// 1 block x 1024: inclusive Hillis-Steele -> exclusive base, cursor copy, nlv
__global__ void k_scan(const int* __restrict__ hist, int* __restrict__ base,
                       int* __restrict__ cursor, int* __restrict__ nlv) {
    __shared__ int tmp[1024];
    int t = threadIdx.x;
    int v = hist[t];
    tmp[t] = v;
    __syncthreads();
    for (int off = 1; off < 1024; off <<= 1) {
        int y = (t >= off) ? tmp[t - off] : 0;
        __syncthreads();
        tmp[t] += y;
        __syncthreads();
    }
    int inc = tmp[t];
    base[t] = inc - v;
    cursor[t] = inc - v;
    if (t == 1023) base[1024] = inc;
    if (v > 0) atomicMax(nlv, t + 1);
}

// ---------------------------------------------------------------------------
// Kernel 1c: LDS-staged scatter — one ranged global RMW per (block, bin).
// Within-level order is arbitrary (any permutation of a level is valid).
// ---------------------------------------------------------------------------
__global__ void k_scatter(const int* __restrict__ depth, int* __restrict__ cursor,
                          int* __restrict__ order) {
    __shared__ int lh[1024];
    __shared__ int lbase[1024];
    int tid = threadIdx.x;
    int g = blockIdx.x * 256 + tid;
    int d = depth[g];
    for (int t = tid; t < 1024; t += 256) lh[t] = 0;
    __syncthreads();
    int lrank = atomicAdd(&lh[d], 1);      // LDS atomic
    __syncthreads();
    for (int t = tid; t < 1024; t += 256)
        if (lh[t] > 0) lbase[t] = atomicAdd(&cursor[t], lh[t]);
    __syncthreads();
    order[lbase[d] + lrank] = g;
}

// ---------------------------------------------------------------------------
// Kernel 2: TE2 = type_emb @ w_ihT (300x768), PE2 = pos_table @ w_ihT (1000x768)
// ---------------------------------------------------------------------------
__global__ void k_table_gemm(const float* __restrict__ type_emb, const float* __restrict__ pos_table,
                             const float* __restrict__ w_ihT,
                             float* __restrict__ TE2, float* __restrict__ PE2) {
    __shared__ float row[D];
    int r = blockIdx.x;
    const float* src;
    float* dst;
    if (r < 300) { src = type_emb + (size_t)r * D;          dst = TE2 + (size_t)r * G3; }
    else         { src = pos_table + (size_t)(r - 300) * D; dst = PE2 + (size_t)(r - 300) * G3; }
    int k = threadIdx.x;
    row[k] = src[k];
    __syncthreads();
    float a0 = 0.f, a1 = 0.f, a2 = 0.f;
#pragma unroll 8
    for (int d = 0; d < D; ++d) {
        float p = row[d];
        const float* w = w_ihT + d * G3;
        a0 += p * w[k];
        a1 += p * w[k + 256];
        a2 += p * w[k + 512];
    }
    dst[k] = a0; dst[k + 256] = a1; dst[k + 512] = a2;
}

// ---------------------------------------------------------------------------
// Kernel 3: output columns [0, D)
// ---------------------------------------------------------------------------
__global__ void k_embed_out(const int* __restrict__ node_types, const int* __restrict__ child_pos,
                            const int* __restrict__ node_vals, const int* __restrict__ offsets,
                            const float* __restrict__ type_emb, const float* __restrict__ pos_table,
                            const float* __restrict__ token_emb, float* __restrict__ out, int Ltot) {
    int tid = threadIdx.x;
    int bag = blockIdx.x * 4 + (tid >> 6);
    int q   = (tid & 63) * 4;
    int b = bag >> 10;
    int i = bag & 1023;
    int t = node_types[bag];
    int c = child_pos[bag];
    int start = offsets[bag];
    int end   = (bag + 1 < NUM_BAGS) ? offsets[bag + 1] : Ltot;

    float4 s = make_float4(0.f, 0.f, 0.f, 0.f);
    for (int l = start; l < end; ++l) {
        float4 v = *(const float4*)(token_emb + (size_t)node_vals[l] * D + q);
        s.x += v.x; s.y += v.y; s.z += v.z; s.w += v.w;
    }
    int cnt = end - start; if (cnt < 1) cnt = 1;
    float inv = 4.0f / (float)cnt;
    float4 a = *(const float4*)(type_emb + (size_t)t * D + q);
    float4 p = *(const float4*)(pos_table + (size_t)c * D + q);
    float4 r;
    r.x = 4.f * a.x + 0.25f * p.x + inv * s.x;
    r.y = 4.f * a.y + 0.25f * p.y + inv * s.y;
    r.z = 4.f * a.z + 0.25f * p.z + inv * s.z;
    r.w = 4.f * a.w + 0.25f * p.w + inv * s.w;
    *(float4*)(out + ((size_t)i * B + b) * OUTW + q) = r;
}

// ---------------------------------------------------------------------------
// Kernel 4: level-scheduled GRU, NB=12 weight-pass batching (R2 core,
// known-correct), with the level barrier replaced by cooperative-groups
// grid.sync() — the harness-sanctioned grid barrier. 256 blocks x 768
// threads x 55.8 KB LDS = exactly 1 block/CU, co-resident by construction.
// All blocks execute identical sync counts (nlv is uniform device data).
// ---------------------------------------------------------------------------
__global__ void __launch_bounds__(768, 3) k_gru_lvl(
        const int* __restrict__ node_types, const int* __restrict__ child_pos,
        const int* __restrict__ last_parent,
        const float* __restrict__ TE2, const float* __restrict__ PE2,
        const uint32* __restrict__ wpack,
        const float* __restrict__ b_ih, const float* __restrict__ b_hh,
        float* __restrict__ out,
        const int* __restrict__ order, const int* __restrict__ lvlbase,
        const int* __restrict__ nlvp) {
    __shared__ __align__(16) uint32 sp[NB][128];   // packed f16 parent h
    __shared__ float gbuf[NB][G3];                 // r,z: gi+gh ; n: gh
    __shared__ float gni[NB][H];                   // n: gi part
    __shared__ int   meta[NB][2];                  // g, parent

    cg::grid_group grid = cg::this_grid();

    const int j = threadIdx.x;
    const int bid = blockIdx.x;
    const float bi = b_ih[j], bh = b_hh[j];
    const int nlv = *nlvp;

    for (int L = 0; L < nlv; ++L) {
        const int s = lvlbase[L], e = lvlbase[L + 1];
        const int nG = (e - s + NB - 1) / NB;
        for (int q = bid; q < nG; q += NBLK) {
            const int k0 = s + q * NB;
            const int cn = min(NB, e - k0);
            if (j < cn) {
                int g = order[k0 + j];
                meta[j][0] = g;
                meta[j][1] = last_parent[g];
            }
            __syncthreads();

            const int lim = cn << 8;               // cn*256
            // parent h rows -> f32 regs (pvr) + packed f16 pairs -> sp
            float pvr[4];
#pragma unroll
            for (int u = 0; u < 4; ++u) {
                const int qq = j + u * 768;
                float hv = 0.f;
                if (qq < lim) {
                    const int n = qq >> 8, jj = qq & 255;
                    const int g = meta[n][0];
                    const int i = g & (N - 1), b = g >> 10;
                    const int p = meta[n][1];
                    if (i > 0 && (unsigned)p < (unsigned)i)
                        hv = out[((size_t)p * B + b) * OUTW + D + jj];
                    float ho = __shfl_xor(hv, 1);
                    if (!(jj & 1)) {
                        h2_t v2 = { (_Float16)hv, (_Float16)ho };
                        sp[n][jj >> 1] = __builtin_bit_cast(uint32, v2);
                    }
                }
                pvr[u] = hv;
            }

            // gi = 4*te + 0.25*pe + bi per node (issued before the dot)
            float gi[NB];
#pragma unroll
            for (int n = 0; n < NB; ++n) {
                float te = 0.f, pe = 0.f;
                if (n < cn) {
                    const int g = meta[n][0];
                    te = TE2[(size_t)node_types[g] * G3 + j];
                    pe = PE2[(size_t)child_pos[g] * G3 + j];
                }
                gi[n] = 4.f * te + 0.25f * pe + bi;
            }

            float acc[NB];
#pragma unroll
            for (int n = 0; n < NB; ++n) acc[n] = 0.f;
            __syncthreads();                       // sp ready

            // ---- batched dot: one wpack stream feeds NB nodes ----
#pragma unroll 4
            for (int m = 0; m < 128; m += 4) {
                const uint32 w0 = wpack[(m + 0) * G3 + j];
                const uint32 w1 = wpack[(m + 1) * G3 + j];
                const uint32 w2 = wpack[(m + 2) * G3 + j];
                const uint32 w3 = wpack[(m + 3) * G3 + j];
#pragma unroll
                for (int n = 0; n < NB; ++n) {
                    const uint4 h4 = *(const uint4*)(&sp[n][m]);
                    acc[n] = dot2f(w0, h4.x, acc[n]);
                    acc[n] = dot2f(w1, h4.y, acc[n]);
                    acc[n] = dot2f(w2, h4.z, acc[n]);
                    acc[n] = dot2f(w3, h4.w, acc[n]);
                }
            }

#pragma unroll
            for (int n = 0; n < NB; ++n) {
                if (n < cn) {
                    const float gh = acc[n] + bh;
                    if (j < 512) gbuf[n][j] = gi[n] + gh;
                    else { gbuf[n][j] = gh; gni[n][j - 512] = gi[n]; }
                }
            }
            __syncthreads();                       // gbuf ready

            // ---- activations + h store ----
#pragma unroll
            for (int u = 0; u < 4; ++u) {
                const int qq = j + u * 768;
                if (qq < lim) {
                    const int n = qq >> 8, jj = qq & 255;
                    const float r  = sigmoidf_(gbuf[n][jj]);
                    const float z  = sigmoidf_(gbuf[n][H + jj]);
                    const float nn = tanhf(gni[n][jj] + r * gbuf[n][2 * H + jj]);
                    const float h  = (1.f - z) * nn + z * pvr[u];
                    const int g = meta[n][0];
                    const int i = g & (N - 1), b = g >> 10;
                    out[((size_t)i * B + b) * OUTW + D + jj] = h;
                }
            }
            __syncthreads();                       // protect meta/sp/gbuf reuse
        }
        // ---- level barrier: sanctioned grid-wide sync ----
        if (L + 1 < nlv) grid.sync();
    }
}

// ---------------------------------------------------------------------------
extern "C" void kernel_launch(void* const* d_in, const int* in_sizes, int n_in,
                              void* d_out, int out_size, void* d_ws, size_t ws_size,
                              hipStream_t stream) {
    const int*   node_types  = (const int*)d_in[0];
    const int*   node_vals   = (const int*)d_in[1];
    const int*   offsets     = (const int*)d_in[2];
    const int*   last_parent = (const int*)d_in[3];
    const int*   child_pos   = (const int*)d_in[4];
    const float* type_emb    = (const float*)d_in[5];
    const float* pos_table   = (const float*)d_in[6];
    const float* token_emb   = (const float*)d_in[7];
    const float* w_ih        = (const float*)d_in[8];
    const float* w_hh        = (const float*)d_in[9];
    const float* b_ih        = (const float*)d_in[10];
    const float* b_hh        = (const float*)d_in[11];
    float* out = (float*)d_out;

    // Workspace: w_ihT | TE2 | PE2 | wpack | depth | order | hist | lvlbase |
    //            cursor | nlv   (~6.0 MB)
    float*  ws      = (float*)d_ws;
    float*  w_ihT   = ws;
    float*  TE2     = w_ihT + (size_t)G3 * D;
    float*  PE2     = TE2 + (size_t)300 * G3;
    uint32* wpack   = (uint32*)(PE2 + (size_t)1000 * G3);
    int*    depth   = (int*)(wpack + (size_t)G3 * 128);
    int*    order   = depth + NUM_BAGS;
    int*    hist    = order + NUM_BAGS;
    int*    lvlbase = hist + 1024;          // 1025 ints
    int*    cursor  = lvlbase + 1025;
    int*    nlv     = cursor + 1024;
    int Ltot = in_sizes[1];

    hipLaunchKernelGGL(k_prep, dim3((G3 * D + 255) / 256), dim3(256), 0, stream,
                       w_ih, w_hh, w_ihT, wpack, hist, nlv);
    hipLaunchKernelGGL(k_depth, dim3(B), dim3(256), 0, stream, last_parent, depth, hist);
    hipLaunchKernelGGL(k_scan, dim3(1), dim3(1024), 0, stream, hist, lvlbase, cursor, nlv);
    hipLaunchKernelGGL(k_scatter, dim3(NUM_BAGS / 256), dim3(256), 0, stream, depth, cursor, order);
    hipLaunchKernelGGL(k_table_gemm, dim3(1300), dim3(256), 0, stream,
                       type_emb, pos_table, w_ihT, TE2, PE2);
    hipLaunchKernelGGL(k_embed_out, dim3(NUM_BAGS / 4), dim3(256), 0, stream,
                       node_types, child_pos, node_vals, offsets,
                       type_emb, pos_table, token_emb, out, Ltot);

    void* args[] = {
        (void*)&node_types, (void*)&child_pos, (void*)&last_parent,
        (void*)&TE2, (void*)&PE2, (void*)&wpack,
        (void*)&b_ih, (void*)&b_hh, (void*)&out,
        (void*)&order, (void*)&lvlbase, (void*)&nlv
    };
    hipLaunchCooperativeKernel((const void*)k_gru_lvl, dim3(NBLK), dim3(768),
                               args, 0, stream);
}

// Round 5
// 1164.847 us; speedup vs baseline: 2.2883x; 1.3373x over previous
//
#include <hip/hip_runtime.h>
#include <hip/hip_cooperative_groups.h>
#include <math.h>

namespace cg = cooperative_groups;

#define B 64
#define N 1024
#define D 256
#define H 256
#define G3 768            // 3*H
#define NUM_BAGS (B*N)
#define OUTW (D+H)
#define NBLK 256          // persistent blocks, one per CU (cooperative)
#define GM 16             // nodes per group (MFMA M)

typedef _Float16 h2_t __attribute__((ext_vector_type(2)));
typedef _Float16 f16x8 __attribute__((ext_vector_type(8)));
typedef float f32x4 __attribute__((ext_vector_type(4)));
typedef unsigned int uint32;

__device__ __forceinline__ float sigmoidf_(float x) { return 1.0f / (1.0f + expf(-x)); }

__device__ __forceinline__ void ld8(const float* __restrict__ p, float* d) {
    float4 a = *(const float4*)p, b = *(const float4*)(p + 4);
    d[0]=a.x; d[1]=a.y; d[2]=a.z; d[3]=a.w; d[4]=b.x; d[5]=b.y; d[6]=b.z; d[7]=b.w;
}

// ---------------------------------------------------------------------------
// Kernel 1: w_ihT transpose, whh16 row-major f16 pack, zero hist/nlv
// whh16[n*128 + m] = pack_f16(w_hh[n][2m], w_hh[n][2m+1])  (row-major in k)
// ---------------------------------------------------------------------------
__global__ void k_prep(const float* __restrict__ w_ih, const float* __restrict__ w_hh,
                       float* __restrict__ w_ihT, uint32* __restrict__ whh16,
                       int* __restrict__ hist, int* __restrict__ nlv) {
    int idx = blockIdx.x * blockDim.x + threadIdx.x;
    if (idx < G3 * D) {
        int j = idx / D;
        int d = idx % D;
        w_ihT[d * G3 + j] = w_ih[idx];
    }
    if (idx < G3 * 128) {
        float w0 = w_hh[2 * idx];
        float w1 = w_hh[2 * idx + 1];
        h2_t v = { (_Float16)w0, (_Float16)w1 };
        whh16[idx] = __builtin_bit_cast(uint32, v);
    }
    if (idx < 1024) hist[idx] = 0;
    if (idx == 0) *nlv = 0;
}

// ---------------------------------------------------------------------------
// Kernel 1b: depth[b][i] = depth[parent]+1 + LDS histogram (spread RMWs)
// ---------------------------------------------------------------------------
__global__ void k_depth(const int* __restrict__ lp_all, int* __restrict__ depth,
                        int* __restrict__ hist) {
    __shared__ int slp[N];
    __shared__ int sd[N];
    __shared__ int lh[1024];
    int b = blockIdx.x;
    for (int t = threadIdx.x; t < N; t += 256) {
        slp[t] = lp_all[(size_t)b * N + t];
        lh[t] = 0;
    }
    __syncthreads();
    if (threadIdx.x == 0) {
        sd[0] = 0;
        for (int i = 1; i < N; ++i) {
            int p = slp[i];
            sd[i] = ((unsigned)p < (unsigned)i) ? sd[p] + 1 : 0;
        }
    }
    __syncthreads();
    for (int t = threadIdx.x; t < N; t += 256) {
        depth[(size_t)b * N + t] = sd[t];
        atomicAdd(&lh[sd[t]], 1);
    }
    __syncthreads();
    for (int t = threadIdx.x; t < 1024; t += 256)
        if (lh[t] > 0) atomicAdd(&hist[t], lh[t]);
}

// 1 block x 1024: inclusive Hillis-Steele -> exclusive base, cursor copy, nlv
__global__ void k_scan(const int* __restrict__ hist, int* __restrict__ base,
                       int* __restrict__ cursor, int* __restrict__ nlv) {
    __shared__ int tmp[1024];
    int t = threadIdx.x;
    int v = hist[t];
    tmp[t] = v;
    __syncthreads();
    for (int off = 1; off < 1024; off <<= 1) {
        int y = (t >= off) ? tmp[t - off] : 0;
        __syncthreads();
        tmp[t] += y;
        __syncthreads();
    }
    int inc = tmp[t];
    base[t] = inc - v;
    cursor[t] = inc - v;
    if (t == 1023) base[1024] = inc;
    if (v > 0) atomicMax(nlv, t + 1);
}

// ---------------------------------------------------------------------------
// Kernel 1c: LDS-staged scatter — one ranged global RMW per (block, bin)
// ---------------------------------------------------------------------------
__global__ void k_scatter(const int* __restrict__ depth, int* __restrict__ cursor,
                          int* __restrict__ order) {
    __shared__ int lh[1024];
    __shared__ int lbase[1024];
    int tid = threadIdx.x;
    int g = blockIdx.x * 256 + tid;
    int d = depth[g];
    for (int t = tid; t < 1024; t += 256) lh[t] = 0;
    __syncthreads();
    int lrank = atomicAdd(&lh[d], 1);
    __syncthreads();
    for (int t = tid; t < 1024; t += 256)
        if (lh[t] > 0) lbase[t] = atomicAdd(&cursor[t], lh[t]);
    __syncthreads();
    order[lbase[d] + lrank] = g;
}

// ---------------------------------------------------------------------------
// Kernel 2: TE2/PE2 with scale+bias FOLDED:
//  type rows:  TE2[t][k]     = 4*(type_emb@w_ihT) + bi[k] + bh[k]   (k < 512)
//              TE2[t][k]     = 4*(...) + bi[k]                      (k >= 512)
//  pos rows:   PE2[c][k]     = 0.25*(pos@w_ihT)
// Activation then needs only TE2+PE2+gh (+bh for n-gate inside r*()).
// ---------------------------------------------------------------------------
__global__ void k_table_gemm(const float* __restrict__ type_emb, const float* __restrict__ pos_table,
                             const float* __restrict__ w_ihT,
                             const float* __restrict__ b_ih, const float* __restrict__ b_hh,
                             float* __restrict__ TE2, float* __restrict__ PE2) {
    __shared__ float row[D];
    int r = blockIdx.x;
    const float* src;
    float* dst;
    bool isType = (r < 300);
    if (isType) { src = type_emb + (size_t)r * D;          dst = TE2 + (size_t)r * G3; }
    else        { src = pos_table + (size_t)(r - 300) * D; dst = PE2 + (size_t)(r - 300) * G3; }
    int k = threadIdx.x;
    row[k] = src[k];
    __syncthreads();
    float a0 = 0.f, a1 = 0.f, a2 = 0.f;
#pragma unroll 8
    for (int d = 0; d < D; ++d) {
        float p = row[d];
        const float* w = w_ihT + d * G3;
        a0 += p * w[k];
        a1 += p * w[k + 256];
        a2 += p * w[k + 512];
    }
    if (isType) {
        dst[k]       = 4.f * a0 + b_ih[k]       + b_hh[k];
        dst[k + 256] = 4.f * a1 + b_ih[k + 256] + b_hh[k + 256];
        dst[k + 512] = 4.f * a2 + b_ih[k + 512];
    } else {
        dst[k] = 0.25f * a0; dst[k + 256] = 0.25f * a1; dst[k + 512] = 0.25f * a2;
    }
}

// ---------------------------------------------------------------------------
// Kernel 3: output columns [0, D)
// ---------------------------------------------------------------------------
__global__ void k_embed_out(const int* __restrict__ node_types, const int* __restrict__ child_pos,
                            const int* __restrict__ node_vals, const int* __restrict__ offsets,
                            const float* __restrict__ type_emb, const float* __restrict__ pos_table,
                            const float* __restrict__ token_emb, float* __restrict__ out, int Ltot) {
    int tid = threadIdx.x;
    int bag = blockIdx.x * 4 + (tid >> 6);
    int q   = (tid & 63) * 4;
    int b = bag >> 10;
    int i = bag & 1023;
    int t = node_types[bag];
    int c = child_pos[bag];
    int start = offsets[bag];
    int end   = (bag + 1 < NUM_BAGS) ? offsets[bag + 1] : Ltot;

    float4 s = make_float4(0.f, 0.f, 0.f, 0.f);
    for (int l = start; l < end; ++l) {
        float4 v = *(const float4*)(token_emb + (size_t)node_vals[l] * D + q);
        s.x += v.x; s.y += v.y; s.z += v.z; s.w += v.w;
    }
    int cnt = end - start; if (cnt < 1) cnt = 1;
    float inv = 4.0f / (float)cnt;
    float4 a = *(const float4*)(type_emb + (size_t)t * D + q);
    float4 p = *(const float4*)(pos_table + (size_t)c * D + q);
    float4 r;
    r.x = 4.f * a.x + 0.25f * p.x + inv * s.x;
    r.y = 4.f * a.y + 0.25f * p.y + inv * s.y;
    r.z = 4.f * a.z + 0.25f * p.z + inv * s.z;
    r.w = 4.f * a.w + 0.25f * p.w + inv * s.w;
    *(float4*)(out + ((size_t)i * B + b) * OUTW + q) = r;
}

// ---------------------------------------------------------------------------
// Kernel 4: level-scheduled GRU on MFMA. Per group: 16 nodes, gates =
// [16x256 f16 h-parents] x [256x768 f16 w_hh^T] via mfma_f32_16x16x32_f16.
// Weights live register-resident per wave (8 waves x 6 N-tiles x 8 K-steps
// x 16B = 192 VGPR) — loaded ONCE, never re-streamed (the R1 failure is
// avoided by __launch_bounds__(512,2) giving a 256-VGPR budget).
// A-fragments: 8 ds_read_b128/wave/group from an 8.4 KB LDS h-tile —
// 72x less LDS delivery than the dot2 version (R4's real bottleneck).
// Fragment maps (m89/m91-verified family): A row=l&15, k=(l>>4)*8+j;
// B col=l&15, k=(l>>4)*8+j; C/D col=l&15, row=(l>>4)*4+reg.
// ---------------------------------------------------------------------------
__global__ void __launch_bounds__(512, 2) k_gru_lvl(
        const int* __restrict__ node_types, const int* __restrict__ child_pos,
        const int* __restrict__ last_parent,
        const float* __restrict__ TE2, const float* __restrict__ PE2,
        const uint32* __restrict__ whh16,
        const float* __restrict__ b_hh,
        float* __restrict__ out,
        const int* __restrict__ order, const int* __restrict__ lvlbase,
        const int* __restrict__ nlvp) {
    __shared__ __align__(16) _Float16 spA[GM * 264];   // h parents, row stride 264
    __shared__ float gbuf[GM * 772];                   // gates f32, row stride 772
    __shared__ int   meta[GM][4];                      // g, parent(-1 invalid), type, cpos

    cg::grid_group grid = cg::this_grid();

    const int j = threadIdx.x;
    const int lane = j & 63;
    const int w = j >> 6;                 // wave 0..7, owns cols [w*96, w*96+96)
    const int lr = lane & 15;             // fragment row/col index
    const int lu = lane >> 4;             // fragment k-group
    const int nlv = *nlvp;

    // ---- register-resident weights: 48 x uint4 = 192 VGPRs ----
    uint4 bw[6][8];
#pragma unroll
    for (int t = 0; t < 6; ++t) {
#pragma unroll
        for (int s = 0; s < 8; ++s) {
            const int n = w * 96 + t * 16 + lr;
            bw[t][s] = *(const uint4*)(whh16 + (size_t)n * 128 + s * 16 + lu * 4);
        }
    }

    for (int L = 0; L < nlv; ++L) {
        const int s0 = lvlbase[L], e = lvlbase[L + 1];
        const int nG = (e - s0 + GM - 1) / GM;
        for (int q = blockIdx.x; q < nG; q += NBLK) {
            const int k0 = s0 + q * GM;
            const int cn = min(GM, e - k0);

            // ---- phase 1: meta ----
            if (j < GM) {
                int g = (j < cn) ? order[k0 + j] : -1;
                int pp = -1, ty = 0, cpos = 0;
                if (g >= 0) {
                    const int i = g & (N - 1);
                    const int p = last_parent[g];
                    if (i > 0 && (unsigned)p < (unsigned)i) pp = p;
                    ty = node_types[g]; cpos = child_pos[g];
                }
                meta[j][0] = g; meta[j][1] = pp; meta[j][2] = ty; meta[j][3] = cpos;
            }
            __syncthreads();

            // ---- phase 2: gather parent h -> f16 LDS tile ----
            {
                const int n = j >> 5, c0 = (j & 31) * 8;
                const int g = meta[n][0], p = meta[n][1];
                float hv[8] = {0.f,0.f,0.f,0.f,0.f,0.f,0.f,0.f};
                if (p >= 0) {
                    const int b = g >> 10;
                    ld8(out + ((size_t)p * B + b) * OUTW + D + c0, hv);
                }
                h2_t v0 = {(_Float16)hv[0], (_Float16)hv[1]};
                h2_t v1 = {(_Float16)hv[2], (_Float16)hv[3]};
                h2_t v2 = {(_Float16)hv[4], (_Float16)hv[5]};
                h2_t v3 = {(_Float16)hv[6], (_Float16)hv[7]};
                uint4 pk = { __builtin_bit_cast(uint32, v0), __builtin_bit_cast(uint32, v1),
                             __builtin_bit_cast(uint32, v2), __builtin_bit_cast(uint32, v3) };
                *(uint4*)(&spA[n * 264 + c0]) = pk;
            }
            __syncthreads();

            // ---- phase 3: MFMA K-loop ----
            {
                f32x4 acc[6];
#pragma unroll
                for (int t = 0; t < 6; ++t) acc[t] = (f32x4){0.f, 0.f, 0.f, 0.f};
#pragma unroll
                for (int s = 0; s < 8; ++s) {
                    const uint4 a4 = *(const uint4*)(&spA[lr * 264 + s * 32 + lu * 8]);
                    const f16x8 af = __builtin_bit_cast(f16x8, a4);
#pragma unroll
                    for (int t = 0; t < 6; ++t) {
                        acc[t] = __builtin_amdgcn_mfma_f32_16x16x32_f16(
                            af, __builtin_bit_cast(f16x8, bw[t][s]), acc[t], 0, 0, 0);
                    }
                }
#pragma unroll
                for (int t = 0; t < 6; ++t) {
#pragma unroll
                    for (int qd = 0; qd < 4; ++qd) {
                        const int row = lu * 4 + qd;
                        const int col = w * 96 + t * 16 + lr;
                        gbuf[row * 772 + col] = acc[t][qd];
                    }
                }
            }
            __syncthreads();

            // ---- phase 4: activation + h store ----
            {
                const int n = j >> 5, c0 = (j & 31) * 8;
                const int g = meta[n][0];
                if (g >= 0) {
                    const int b = g >> 10, i = g & (N - 1);
                    const int p = meta[n][1], ty = meta[n][2], cp_ = meta[n][3];
                    float pv[8] = {0.f,0.f,0.f,0.f,0.f,0.f,0.f,0.f};
                    if (p >= 0)
                        ld8(out + ((size_t)p * B + b) * OUTW + D + c0, pv);
                    const float* gb = gbuf + n * 772;
                    const float* te = TE2 + (size_t)ty * G3;
                    const float* pe = PE2 + (size_t)cp_ * G3;
                    float ga[8], ta[8], pa[8], rr[8], zz[8], hr[8];
                    ld8(gb + c0, ga); ld8(te + c0, ta); ld8(pe + c0, pa);
#pragma unroll
                    for (int u = 0; u < 8; ++u) rr[u] = sigmoidf_(ga[u] + ta[u] + pa[u]);
                    ld8(gb + 256 + c0, ga); ld8(te + 256 + c0, ta); ld8(pe + 256 + c0, pa);
#pragma unroll
                    for (int u = 0; u < 8; ++u) zz[u] = sigmoidf_(ga[u] + ta[u] + pa[u]);
                    ld8(gb + 512 + c0, ga); ld8(te + 512 + c0, ta); ld8(pe + 512 + c0, pa);
                    float bn[8];
                    ld8(b_hh + 512 + c0, bn);
#pragma unroll
                    for (int u = 0; u < 8; ++u) {
                        const float nn = tanhf(ta[u] + pa[u] + rr[u] * (ga[u] + bn[u]));
                        hr[u] = (1.f - zz[u]) * nn + zz[u] * pv[u];
                    }
                    float* orow = out + ((size_t)i * B + b) * OUTW + D + c0;
                    *(float4*)orow       = make_float4(hr[0], hr[1], hr[2], hr[3]);
                    *(float4*)(orow + 4) = make_float4(hr[4], hr[5], hr[6], hr[7]);
                }
            }
            __syncthreads();
        }
        // ---- level barrier ----
        if (L + 1 < nlv) grid.sync();
    }
}

// ---------------------------------------------------------------------------
extern "C" void kernel_launch(void* const* d_in, const int* in_sizes, int n_in,
                              void* d_out, int out_size, void* d_ws, size_t ws_size,
                              hipStream_t stream) {
    const int*   node_types  = (const int*)d_in[0];
    const int*   node_vals   = (const int*)d_in[1];
    const int*   offsets     = (const int*)d_in[2];
    const int*   last_parent = (const int*)d_in[3];
    const int*   child_pos   = (const int*)d_in[4];
    const float* type_emb    = (const float*)d_in[5];
    const float* pos_table   = (const float*)d_in[6];
    const float* token_emb   = (const float*)d_in[7];
    const float* w_ih        = (const float*)d_in[8];
    const float* w_hh        = (const float*)d_in[9];
    const float* b_ih        = (const float*)d_in[10];
    const float* b_hh        = (const float*)d_in[11];
    float* out = (float*)d_out;

    // Workspace: w_ihT | TE2 | PE2 | whh16 | depth | order | hist | lvlbase |
    //            cursor | nlv   (~5.7 MB)
    float*  ws      = (float*)d_ws;
    float*  w_ihT   = ws;
    float*  TE2     = w_ihT + (size_t)G3 * D;
    float*  PE2     = TE2 + (size_t)300 * G3;
    uint32* whh16   = (uint32*)(PE2 + (size_t)1000 * G3);
    int*    depth   = (int*)(whh16 + (size_t)G3 * 128);
    int*    order   = depth + NUM_BAGS;
    int*    hist    = order + NUM_BAGS;
    int*    lvlbase = hist + 1024;          // 1025 ints
    int*    cursor  = lvlbase + 1025;
    int*    nlv     = cursor + 1024;
    int Ltot = in_sizes[1];

    hipLaunchKernelGGL(k_prep, dim3((G3 * D + 255) / 256), dim3(256), 0, stream,
                       w_ih, w_hh, w_ihT, whh16, hist, nlv);
    hipLaunchKernelGGL(k_depth, dim3(B), dim3(256), 0, stream, last_parent, depth, hist);
    hipLaunchKernelGGL(k_scan, dim3(1), dim3(1024), 0, stream, hist, lvlbase, cursor, nlv);
    hipLaunchKernelGGL(k_scatter, dim3(NUM_BAGS / 256), dim3(256), 0, stream, depth, cursor, order);
    hipLaunchKernelGGL(k_table_gemm, dim3(1300), dim3(256), 0, stream,
                       type_emb, pos_table, w_ihT, b_ih, b_hh, TE2, PE2);
    hipLaunchKernelGGL(k_embed_out, dim3(NUM_BAGS / 4), dim3(256), 0, stream,
                       node_types, child_pos, node_vals, offsets,
                       type_emb, pos_table, token_emb, out, Ltot);

    void* args[] = {
        (void*)&node_types, (void*)&child_pos, (void*)&last_parent,
        (void*)&TE2, (void*)&PE2, (void*)&whh16,
        (void*)&b_hh, (void*)&out,
        (void*)&order, (void*)&lvlbase, (void*)&nlv
    };
    hipLaunchCooperativeKernel((const void*)k_gru_lvl, dim3(NBLK), dim3(512),
                               args, 0, stream);
}